// Round 8
// baseline (608.438 us; speedup 1.0000x reference)
//
#include <hip/hip_runtime.h>
#include <hip/hip_bf16.h>

typedef __hip_bfloat16 bf16;
typedef __attribute__((ext_vector_type(8))) short s16x8;   // 8 bf16 = 4 VGPRs
typedef __attribute__((ext_vector_type(4))) float f32x4;

#define MFMA16x16x32(A, B, C) __builtin_amdgcn_mfma_f32_16x16x32_bf16((A), (B), (C), 0, 0, 0)

__device__ __forceinline__ void async_copy16(const bf16* g, bf16* l) {
  __builtin_amdgcn_global_load_lds(
      (const __attribute__((address_space(1))) void*)g,
      (__attribute__((address_space(3))) void*)l, 16, 0, 0);
}

// butterfly over lanes ^16 — DS swizzle BitMode
__device__ __forceinline__ float swz_x16(float x) {
  return __int_as_float(__builtin_amdgcn_ds_swizzle(__float_as_int(x), 0x401f));
}

// XOR-swizzle: rows of 64 bf16, 16B chunks, chunk' = chunk ^ (row&7)
__device__ __forceinline__ int SW(int row, int chunk) {
  return row * 64 + (((chunk) ^ (row & 7)) << 3);
}
// XOR-swizzle for 32-wide rows (P tiles): chunk' = chunk ^ (row&3)
__device__ __forceinline__ int SW32(int row, int chunk) {
  return row * 32 + (((chunk) ^ (row & 3)) << 3);
}

// ---------------------------------------------------------------------------
// One fused cast kernel: 5 segments (w_qkv, w_out, w1, w2, src), f32 -> bf16
// ---------------------------------------------------------------------------
__global__ __launch_bounds__(256)
void cast_all_kernel(const float* __restrict__ p0, bf16* __restrict__ q0,
                     const float* __restrict__ p1, bf16* __restrict__ q1,
                     const float* __restrict__ p2, bf16* __restrict__ q2,
                     const float* __restrict__ p3, bf16* __restrict__ q3,
                     const float* __restrict__ p4, bf16* __restrict__ q4) {
  int blk = blockIdx.x;
  const float* in; bf16* out;
  if (blk < 1728)      { in = p0; out = q0; }
  else if (blk < 2304) { in = p1; out = q1; blk -= 1728; }
  else if (blk < 4608) { in = p2; out = q2; blk -= 2304; }
  else if (blk < 6912) { in = p3; out = q3; blk -= 4608; }
  else                 { in = p4; out = q4; blk -= 6912; }
  const int i = (blk * 256 + threadIdx.x) * 4;
  const float4 f = *(const float4*)(in + i);
  out[i + 0] = (bf16)f.x; out[i + 1] = (bf16)f.y;
  out[i + 2] = (bf16)f.z; out[i + 3] = (bf16)f.w;
}

// ---------------------------------------------------------------------------
// GEMM: C = A[M,K]b @ B[N,K]^T b (+bias f32) (+ReLU) (+fp32 accumulate).
// 128x128 tile, BK=32, 256 threads, global_load_lds width-16 staging (m97).
// ---------------------------------------------------------------------------
template <int RELU, int ACCUM, typename OutT>
__global__ __launch_bounds__(256)
void gemm_bt_kernel(const bf16* __restrict__ A, const bf16* __restrict__ B,
                    const float* __restrict__ bias, OutT* __restrict__ C,
                    int N, int K, int ldb) {
  __shared__ __align__(16) bf16 As[128 * 32];
  __shared__ __align__(16) bf16 Bs[128 * 32];
  const int t = threadIdx.x, lane = t & 63, wave = t >> 6;
  const int wm = (wave >> 1) << 6, wn = (wave & 1) << 6;
  const int col16 = lane & 15, quad = lane >> 4;
  const int bm = blockIdx.x, bn = blockIdx.y;

  const bf16* Ag = A + (size_t)(bm * 128 + (t >> 2)) * K + (t & 3) * 8;
  const bf16* Bg = B + (size_t)(bn * 128 + (t >> 2)) * ldb + (t & 3) * 8;
  bf16* Asd = As + t * 8;
  bf16* Bsd = Bs + t * 8;

  f32x4 acc[4][4] = {};
  for (int k0 = 0; k0 < K; k0 += 32) {
    __syncthreads();
    async_copy16(Ag + k0, Asd);
    async_copy16(Ag + (size_t)64 * K + k0, Asd + 2048);
    async_copy16(Bg + k0, Bsd);
    async_copy16(Bg + (size_t)64 * ldb + k0, Bsd + 2048);
    asm volatile("s_waitcnt vmcnt(0)" ::: "memory");
    __syncthreads();
    s16x8 af[4], bfr[4];
#pragma unroll
    for (int i = 0; i < 4; i++)
      af[i] = *(const s16x8*)(As + (wm + i * 16 + col16) * 32 + quad * 8);
#pragma unroll
    for (int j = 0; j < 4; j++)
      bfr[j] = *(const s16x8*)(Bs + (wn + j * 16 + col16) * 32 + quad * 8);
#pragma unroll
    for (int i = 0; i < 4; i++)
#pragma unroll
      for (int j = 0; j < 4; j++)
        acc[i][j] = MFMA16x16x32(af[i], bfr[j], acc[i][j]);
  }
  const int row0 = bm * 128 + wm + quad * 4;
  const int col0 = bn * 128 + wn + col16;
#pragma unroll
  for (int j = 0; j < 4; j++) {
    const int col = col0 + j * 16;
    const float bv = ACCUM ? 0.0f : bias[col];
#pragma unroll
    for (int i = 0; i < 4; i++)
#pragma unroll
      for (int r = 0; r < 4; r++) {
        float v = acc[i][j][r] + bv;
        if (RELU) v = fmaxf(v, 0.0f);
        const size_t idx = (size_t)(row0 + i * 16 + r) * N + col;
        if (ACCUM) v += ((const float*)C)[idx];
        C[idx] = (OutT)v;
      }
  }
}

// ---------------------------------------------------------------------------
// Merged QKV GEMM, grid (64, 18): bn<12 -> QK[8192,1536]; bn>=12 -> Vt scatter
// ---------------------------------------------------------------------------
__global__ __launch_bounds__(256)
void gemm_qkv_kernel(const bf16* __restrict__ A, const bf16* __restrict__ B,
                     const float* __restrict__ bias, bf16* __restrict__ QKo,
                     bf16* __restrict__ Vt) {
  __shared__ __align__(16) bf16 As[128 * 32];
  __shared__ __align__(16) bf16 Bs[128 * 32];
  const int t = threadIdx.x, lane = t & 63, wave = t >> 6;
  const int wm = (wave >> 1) << 6, wn = (wave & 1) << 6;
  const int col16 = lane & 15, quad = lane >> 4;
  const int bm = blockIdx.x, bn = blockIdx.y;
  const int K = 768;

  const bf16* Ag = A + (size_t)(bm * 128 + (t >> 2)) * K + (t & 3) * 8;
  const bf16* Bg = B + (size_t)(bn * 128 + (t >> 2)) * K + (t & 3) * 8;
  bf16* Asd = As + t * 8;
  bf16* Bsd = Bs + t * 8;

  f32x4 acc[4][4] = {};
  for (int k0 = 0; k0 < K; k0 += 32) {
    __syncthreads();
    async_copy16(Ag + k0, Asd);
    async_copy16(Ag + (size_t)64 * K + k0, Asd + 2048);
    async_copy16(Bg + k0, Bsd);
    async_copy16(Bg + (size_t)64 * K + k0, Bsd + 2048);
    asm volatile("s_waitcnt vmcnt(0)" ::: "memory");
    __syncthreads();
    s16x8 af[4], bfr[4];
#pragma unroll
    for (int i = 0; i < 4; i++)
      af[i] = *(const s16x8*)(As + (wm + i * 16 + col16) * 32 + quad * 8);
#pragma unroll
    for (int j = 0; j < 4; j++)
      bfr[j] = *(const s16x8*)(Bs + (wn + j * 16 + col16) * 32 + quad * 8);
#pragma unroll
    for (int i = 0; i < 4; i++)
#pragma unroll
      for (int j = 0; j < 4; j++)
        acc[i][j] = MFMA16x16x32(af[i], bfr[j], acc[i][j]);
  }
  const int row0 = bm * 128 + wm + quad * 4;
  const int col0 = bn * 128 + wn + col16;
#pragma unroll
  for (int j = 0; j < 4; j++) {
    const int col = col0 + j * 16;
    const float bv = bias[col];
#pragma unroll
    for (int i = 0; i < 4; i++)
#pragma unroll
      for (int r = 0; r < 4; r++) {
        const float v = acc[i][j][r] + bv;
        const int row = row0 + i * 16 + r;
        if (bn < 12) {
          QKo[(size_t)row * 1536 + col] = (bf16)v;
        } else {
          const int vc = col - 1536;  // 0..767
          Vt[(size_t)((row >> 12) * 12 + (vc >> 6)) * 262144 +
             (vc & 63) * 4096 + (row & 4095)] = (bf16)v;
        }
      }
  }
}

// ---------------------------------------------------------------------------
// Flash attention: 2x2 wave decomposition. Block = 128 q x 64-key tiles;
// wave (qh,kh) handles 64 q x 32 keys -> each LDS K/V byte feeds 2x MACs.
// Fixed-shift log2 softmax (p = exp2(s-16)), per-lane l, one merge at end.
// LDS 32 KB: Ks[64x64] Vs[64x64] (SW), Ps[4][64x32] (SW32).
// ---------------------------------------------------------------------------
__global__ __launch_bounds__(256)
void attn_kernel(const bf16* __restrict__ QK, const bf16* __restrict__ Vt,
                 bf16* __restrict__ ctx) {
  __shared__ __align__(16) bf16 lds[16384];     // 32 KB
  bf16* Ks = lds;                               // [0, 4096)
  bf16* Vs = lds + 4096;                        // [4096, 8192)
  bf16* Ps = lds + 8192;                        // [8192, 16384): 4 x 2048

  const int t = threadIdx.x, lane = t & 63, wave = t >> 6;
  const int col16 = lane & 15, quad = lane >> 4;
  const int qh = wave >> 1, kh = wave & 1;
  const int b = blockIdx.z, h = blockIdx.y;
  const int qbase = blockIdx.x * 128 + qh * 64;

  // Q as B-frags: 4 qtiles x 2 d-halves, pre-scaled by 0.125*log2(e)
  s16x8 bq[4][2];
#pragma unroll
  for (int qt = 0; qt < 4; qt++)
#pragma unroll
    for (int s = 0; s < 2; s++) {
      union { s16x8 v; bf16 hh[8]; } u;
      u.v = *(const s16x8*)(QK + (size_t)(b * 4096 + qbase + qt * 16 + col16) * 1536 +
                            h * 64 + s * 32 + quad * 8);
#pragma unroll
      for (int e = 0; e < 8; e++) u.hh[e] = (bf16)((float)u.hh[e] * 0.18033688f);
      bq[qt][s] = u.v;
    }

  const bf16* kbase = QK + (size_t)(b * 4096) * 1536 + 768 + h * 64;
  const bf16* vbase = Vt + (size_t)(b * 12 + h) * 262144;
  const int srow = t >> 2, cch = t & 3;

  f32x4 o[4][4] = {};                 // O^T [dtile][qtile]
  float l_[4] = {};
  bf16* pw = Ps + wave * 2048;

  for (int k0 = 0; k0 < 4096; k0 += 64) {
    const s16x8 kc0 = *(const s16x8*)(kbase + (size_t)(k0 + srow) * 1536 + cch * 8);
    const s16x8 kc1 = *(const s16x8*)(kbase + (size_t)(k0 + srow) * 1536 + cch * 8 + 32);
    const s16x8 vc0 = *(const s16x8*)(vbase + (size_t)srow * 4096 + k0 + cch * 8);
    const s16x8 vc1 = *(const s16x8*)(vbase + (size_t)srow * 4096 + k0 + cch * 8 + 32);
    __syncthreads();
    *(s16x8*)(Ks + SW(srow, cch)) = kc0;
    *(s16x8*)(Ks + SW(srow, cch + 4)) = kc1;
    *(s16x8*)(Vs + SW(srow, cch)) = vc0;
    *(s16x8*)(Vs + SW(srow, cch + 4)) = vc1;
    __syncthreads();

    // S^T[key][q]: 2 keytiles (within our 32-key half) x 4 qtiles
    f32x4 st[2][4] = {};
#pragma unroll
    for (int s = 0; s < 2; s++) {
      s16x8 ak[2];
#pragma unroll
      for (int kt = 0; kt < 2; kt++)
        ak[kt] = *(const s16x8*)(Ks + SW(kh * 32 + kt * 16 + col16, s * 4 + quad));
#pragma unroll
      for (int kt = 0; kt < 2; kt++)
#pragma unroll
        for (int qt = 0; qt < 4; qt++)
          st[kt][qt] = MFMA16x16x32(ak[kt], bq[qt][s], st[kt][qt]);
    }

    // fixed-shift softmax + P^T store ([64 q][32 k] swizzled, per wave)
#pragma unroll
    for (int qt = 0; qt < 4; qt++) {
      const int q32 = qt * 16 + col16;
#pragma unroll
      for (int kt = 0; kt < 2; kt++) {
        union { unsigned long long u; bf16 hh[4]; } pk;
#pragma unroll
        for (int r = 0; r < 4; r++) {
          const float p = exp2f(st[kt][qt][r] - 16.0f);
          l_[qt] += p;
          pk.hh[r] = (bf16)p;
        }
        const int chunk = kt * 2 + (quad >> 1);
        *(unsigned long long*)(pw + q32 * 32 + ((chunk ^ (q32 & 3)) << 3) +
                               (quad & 1) * 4) = pk.u;
      }
    }
    asm volatile("s_waitcnt lgkmcnt(0)" ::: "memory");

    // O^T += V^T @ P^T  (K=32: our key half)
    s16x8 bp[4];
#pragma unroll
    for (int qt = 0; qt < 4; qt++)
      bp[qt] = *(const s16x8*)(pw + SW32(qt * 16 + col16, quad));
#pragma unroll
    for (int dt = 0; dt < 4; dt++) {
      const s16x8 av = *(const s16x8*)(Vs + SW(dt * 16 + col16, kh * 4 + quad));
#pragma unroll
      for (int qt = 0; qt < 4; qt++)
        o[dt][qt] = MFMA16x16x32(av, bp[qt], o[dt][qt]);
    }
  }

  // ---- merge key-halves, normalize, write ----
  __syncthreads();
  bf16* mb = lds;                                  // [2][64q][64d] bf16 = 16 KB
  float* lb = (float*)(lds + 8192);                // per qh: 64q x 4quad f32
  if (kh == 1) {
#pragma unroll
    for (int qt = 0; qt < 4; qt++) {
      const int q = qt * 16 + col16;
#pragma unroll
      for (int dt = 0; dt < 4; dt++)
#pragma unroll
        for (int r = 0; r < 4; r++)
          mb[qh * 4096 + q * 64 + dt * 16 + quad * 4 + r] = (bf16)o[dt][qt][r];
      lb[qh * 1024 + q * 4 + quad] = l_[qt];
    }
  }
  __syncthreads();
  if (kh == 0) {
    float inv[4];
#pragma unroll
    for (int qt = 0; qt < 4; qt++) {
      const int q = qt * 16 + col16;
      float l = l_[qt] + lb[qh * 1024 + q * 4 + quad];
      l += swz_x16(l);
      l += __shfl_xor(l, 32, 64);
      inv[qt] = 1.0f / l;
    }
#pragma unroll
    for (int qt = 0; qt < 4; qt++) {
      const int q = qt * 16 + col16;
#pragma unroll
      for (int dt = 0; dt < 4; dt++)
#pragma unroll
        for (int r = 0; r < 4; r++)
          o[dt][qt][r] += (float)mb[qh * 4096 + q * 64 + dt * 16 + quad * 4 + r];
    }
    asm volatile("s_waitcnt lgkmcnt(0)" ::: "memory");
    // transposed normalized write into trans region (rows 64q x 64d, SW)
    bf16* tr = lds + 8192 + qh * 4096;
#pragma unroll
    for (int qt = 0; qt < 4; qt++) {
      const int q = qt * 16 + col16;
#pragma unroll
      for (int dt = 0; dt < 4; dt++) {
        union { unsigned long long u; bf16 hh[4]; } pk;
#pragma unroll
        for (int r = 0; r < 4; r++) pk.hh[r] = (bf16)(o[dt][qt][r] * inv[qt]);
        const int chunk = dt * 2 + (quad >> 1);
        *(unsigned long long*)(tr + q * 64 + ((chunk ^ (q & 7)) << 3) +
                               (quad & 1) * 4) = pk.u;
      }
    }
    asm volatile("s_waitcnt lgkmcnt(0)" ::: "memory");
    bf16* dst = ctx + (size_t)(b * 4096 + qbase + lane) * 768 + h * 64;
#pragma unroll
    for (int p = 0; p < 8; p++) {
      const s16x8 val = *(const s16x8*)(tr + lane * 64 + (p << 3));
      *(s16x8*)(dst + (p ^ (lane & 7)) * 8) = val;
    }
  }
}

// ---------------------------------------------------------------------------
// LN variants
// ---------------------------------------------------------------------------
__global__ __launch_bounds__(256)
void add_ln_b_kernel(const float* __restrict__ X, const float* __restrict__ Y,
                     const float* __restrict__ w, const float* __restrict__ b,
                     bf16* __restrict__ out) {
  const int row = blockIdx.x * 4 + (threadIdx.x >> 6);
  const int lane = threadIdx.x & 63;
  const float* x = X + (size_t)row * 768;
  const float* y = Y + (size_t)row * 768;
  float v[12]; float s = 0.0f;
#pragma unroll
  for (int i = 0; i < 3; i++) {
    const int c = lane * 4 + i * 256;
    const float4 xf = *(const float4*)(x + c);
    const float4 yf = *(const float4*)(y + c);
    v[i*4+0]=xf.x+yf.x; v[i*4+1]=xf.y+yf.y; v[i*4+2]=xf.z+yf.z; v[i*4+3]=xf.w+yf.w;
    s += v[i*4]+v[i*4+1]+v[i*4+2]+v[i*4+3];
  }
#pragma unroll
  for (int off = 32; off > 0; off >>= 1) s += __shfl_xor(s, off, 64);
  const float mu = s * (1.0f / 768.0f);
  float var = 0.0f;
#pragma unroll
  for (int i = 0; i < 12; i++) { const float d = v[i] - mu; var += d * d; }
#pragma unroll
  for (int off = 32; off > 0; off >>= 1) var += __shfl_xor(var, off, 64);
  const float rs = rsqrtf(var * (1.0f / 768.0f) + 1e-5f);
#pragma unroll
  for (int i = 0; i < 12; i++) {
    const int c = lane * 4 + (i >> 2) * 256 + (i & 3);
    out[(size_t)row * 768 + c] = (bf16)((v[i] - mu) * rs * w[c] + b[c]);
  }
}

__global__ __launch_bounds__(256)
void add_ln_f_kernel(const bf16* __restrict__ X, const float* __restrict__ Y,
                     const float* __restrict__ w, const float* __restrict__ b,
                     float* __restrict__ out) {
  const int row = blockIdx.x * 4 + (threadIdx.x >> 6);
  const int lane = threadIdx.x & 63;
  const bf16* x = X + (size_t)row * 768;
  const float* y = Y + (size_t)row * 768;
  float v[12]; float s = 0.0f;
#pragma unroll
  for (int i = 0; i < 3; i++) {
    const int c = lane * 4 + i * 256;
    const float4 yf = *(const float4*)(y + c);
    v[i*4+0]=(float)x[c+0]+yf.x; v[i*4+1]=(float)x[c+1]+yf.y;
    v[i*4+2]=(float)x[c+2]+yf.z; v[i*4+3]=(float)x[c+3]+yf.w;
    s += v[i*4]+v[i*4+1]+v[i*4+2]+v[i*4+3];
  }
#pragma unroll
  for (int off = 32; off > 0; off >>= 1) s += __shfl_xor(s, off, 64);
  const float mu = s * (1.0f / 768.0f);
  float var = 0.0f;
#pragma unroll
  for (int i = 0; i < 12; i++) { const float d = v[i] - mu; var += d * d; }
#pragma unroll
  for (int off = 32; off > 0; off >>= 1) var += __shfl_xor(var, off, 64);
  const float rs = rsqrtf(var * (1.0f / 768.0f) + 1e-5f);
#pragma unroll
  for (int i = 0; i < 12; i++) {
    const int c = lane * 4 + (i >> 2) * 256 + (i & 3);
    out[(size_t)row * 768 + c] = (v[i] - mu) * rs * w[c] + b[c];
  }
}

// ---------------------------------------------------------------------------
extern "C" void kernel_launch(void* const* d_in, const int* in_sizes, int n_in,
                              void* d_out, int out_size, void* d_ws, size_t ws_size,
                              hipStream_t stream) {
  (void)in_sizes; (void)n_in; (void)out_size; (void)ws_size;
  const float* src   = (const float*)d_in[0];
  const float* w_qkv = (const float*)d_in[1];
  const float* b_qkv = (const float*)d_in[2];
  const float* w_out = (const float*)d_in[3];
  const float* b_out = (const float*)d_in[4];
  const float* w1    = (const float*)d_in[5];
  const float* b1    = (const float*)d_in[6];
  const float* w2    = (const float*)d_in[7];
  const float* b2    = (const float*)d_in[8];
  const float* ln1w  = (const float*)d_in[9];
  const float* ln1b  = (const float*)d_in[10];
  const float* ln2w  = (const float*)d_in[11];
  const float* ln2b  = (const float*)d_in[12];
  float* out = (float*)d_out;

  // ws layout (peak 64,487,424 B — validated)
  char* ws = (char*)d_ws;
  bf16* wqkvb = (bf16*)ws;                     // 2304*768
  bf16* woutb = (bf16*)(ws + 3538944);         //  768*768
  bf16* w1b   = (bf16*)(ws + 4718592);         // 3072*768
  bf16* w2b   = (bf16*)(ws + 9437184);         //  768*3072
  bf16* srcb  = (bf16*)(ws + 14155776);
  bf16* QK    = (bf16*)(ws + 26738688);
  bf16* Vt    = (bf16*)(ws + 51904512);
  bf16* ctx   = (bf16*)d_out;
  float* attn_out = (float*)(ws + 26738688);   // QK region (dead after attn)
  bf16* x1b   = (bf16*)(ws + 51904512);        // Vt region (dead after attn)
  bf16* hbuf  = (bf16*)(ws + 14155776);        // srcb+ region
  float* ffn  = out;

  // 0) fused casts (w_qkv | w_out | w1 | w2 | src)
  cast_all_kernel<<<13056, 256, 0, stream>>>(w_qkv, wqkvb, w_out, woutb,
                                             w1, w1b, w2, w2b, src, srcb);
  // 1) QK + Vt in one launch
  gemm_qkv_kernel<<<dim3(64, 18), 256, 0, stream>>>(srcb, wqkvb, b_qkv, QK, Vt);
  // 2) ctx = softmax(QK^T/8) V -> d_out
  attn_kernel<<<dim3(32, 12, 2), 256, 0, stream>>>(QK, Vt, ctx);
  // 3) attn_out = ctx @ w_out^T + b_out (f32)
  gemm_bt_kernel<0, 0, float><<<dim3(64, 6), 256, 0, stream>>>(
      ctx, woutb, b_out, attn_out, 768, 768, 768);
  // 4) x1b = LN(src + attn_out)  (bf16)
  add_ln_b_kernel<<<2048, 256, 0, stream>>>(src, attn_out, ln1w, ln1b, x1b);
  // 5/6) FFN, 2 chunks of 1536 h-columns; ffn accumulates f32 in d_out
  for (int c = 0; c < 2; c++) {
    gemm_bt_kernel<1, 0, bf16><<<dim3(64, 12), 256, 0, stream>>>(
        x1b, w1b + (size_t)c * 1536 * 768, b1 + c * 1536, hbuf, 1536, 768, 768);
    if (c == 0)
      gemm_bt_kernel<0, 0, float><<<dim3(64, 6), 256, 0, stream>>>(
          hbuf, w2b + c * 1536, b2, ffn, 768, 1536, 3072);
    else
      gemm_bt_kernel<0, 1, float><<<dim3(64, 6), 256, 0, stream>>>(
          hbuf, w2b + c * 1536, b2, ffn, 768, 1536, 3072);
  }
  // 7) out = LN(x1b + ffn)  (in-place over ffn in d_out)
  add_ln_f_kernel<<<2048, 256, 0, stream>>>(x1b, ffn, ln2w, ln2b, out);
}